// Round 15
// baseline (208.734 us; speedup 1.0000x reference)
//
#include <hip/hip_runtime.h>

#define T_STEPS 512
#define BATCH   2048
#define HID     64
#define IN0     8
#define SPW     16                // seqs per block (MFMA N dim)
#define NBLK    (BATCH / SPW)     // 128 blocks x 8 waves (512 thr)
#define SS      8                 // x-prefetch depth
#define NSS     (T_STEPS / SS)

// 2*log2(e): folded into all weights/biases so tanh needs no input scaling
#define KSC 2.885390081777927f

typedef _Float16 h2 __attribute__((ext_vector_type(2)));
typedef _Float16 h4 __attribute__((ext_vector_type(4)));
typedef _Float16 h8 __attribute__((ext_vector_type(8)));
typedef float    f4 __attribute__((ext_vector_type(4)));

#define MFMA(a, b, c) __builtin_amdgcn_mfma_f32_16x16x32_f16((a), (b), (c), 0, 0, 0)

union F8  { h8 v; h2 p[4]; };
union H4U { h4 v; h2 p[2]; };
union H8Q { h8 v; h4 h[2]; };

__device__ __forceinline__ h2 pkrtz(float a, float b) {
    return __builtin_bit_cast(h2, __builtin_amdgcn_cvt_pkrtz(a, b));
}

// tanh(a) where input kx = KSC*a (pre-scaled via weights):
// 4 instrs/elem (exp2, add, rcp, fma); saturates correctly at +/-inf.
__device__ __forceinline__ float tanh_pre(float kx) {
    float e = __builtin_amdgcn_exp2f(kx);
    return 1.0f - 2.0f * __builtin_amdgcn_rcpf(e + 1.0f);
}

// fragment load with fold-in scale (runs once at init; cost irrelevant)
__device__ __forceinline__ h8 load_frag_f16_s(const float* Wrow, float s) {
    const float4* p = (const float4*)Wrow;
    float4 a = p[0], b = p[1];
    F8 f; f.p[0] = pkrtz(s * a.x, s * a.y); f.p[1] = pkrtz(s * a.z, s * a.w);
          f.p[2] = pkrtz(s * b.x, s * b.y); f.p[3] = pkrtz(s * b.z, s * b.w);
    return f.v;
}

// Barrier draining ONLY lgkmcnt (LDS); x-prefetch globals stay in flight.
// lgkmcnt(0) also retires this step's stable-buffer reads before any wave
// can cross and overwrite them next step (double-buffer race-safety).
#define LDS_BARRIER() asm volatile("s_waitcnt lgkmcnt(0)\n\ts_barrier" ::: "memory")

// Sigma quarter-split (R13 champion): wave owns ONE m-tile mt; its 4
// post-tanh C values pack to an h4 = half of the k-tile (mt>>1) B-fragment
// at the SAME lane. Full B-frag kt = concat(X[2kt], X[2kt+1]). Exchange
// [bf][mt][lane] h4: 8B/lane linear, 0 conflicts (measured R13).
// HW model (R10-R13 fit): lone-wave issue ~6cy/instr, chain latency sets
// the rest. R14 change: split serial MFMA chains into independent
// accumulator pairs + f4 add — L1's 4-chain was the longest path.
__global__ __launch_bounds__(512, 1)
void rnn2_q8s(const float* __restrict__ x,
              const float* __restrict__ Wih0, const float* __restrict__ Whh0,
              const float* __restrict__ bih0, const float* __restrict__ bhh0,
              const float* __restrict__ Wih1, const float* __restrict__ Whh1,
              const float* __restrict__ bih1, const float* __restrict__ bhh1,
              const float* __restrict__ fcw,  const float* __restrict__ fcb,
              float* __restrict__ out) {
    const int tid  = threadIdx.x;
    const int w    = tid >> 6;     // 0-3: L0 quarter mt; 4-7: L1 quarter mt
    const int mt   = w & 3;        // owned m-tile (sigma rows)
    const bool isL0 = (w < 4);     // SIMD k hosts waves k, k+4: L0+L1 pair
    const int lane = tid & 63;
    const int n    = lane & 15;    // seq column / A-row-slot
    const int q    = lane >> 4;
    const int bseq = blockIdx.x * SPW;

    // [bf][mt][lane] h4 quarters; full frag kt = h[2kt],h[2kt+1]. 4KB+4KB.
    __shared__ __align__(16) h4 X0[2][4][64];
    __shared__ __align__(16) h4 X1[2][4][64];
    __shared__ float red[4][SPW];

    // zero-init: H0(-1)=H1(-1)=0 reads at t=0/1 come from these
    { h4 z = {}; X0[w >> 2][mt][lane] = z; X1[w >> 2][mt][lane] = z; }
    __syncthreads();

    const h2 z2 = pkrtz(0.f, 0.f);
    const f4 zero = {0.f, 0.f, 0.f, 0.f};
    const float fcb0 = fcb[0];
    // sigma A-row for this wave's A fragments (A row-slot = n)
    const int ar = 32 * (mt >> 1) + 4 * (mt & 1) + 8 * (n >> 2) + (n & 3);

    if (isL0) {
        // ---------------- layer-0 quarter-wave ----------------
        h8 wh[2], wi;              // KSC-scaled
        f4 bias;
        #pragma unroll
        for (int kt = 0; kt < 2; ++kt)
            wh[kt] = load_frag_f16_s(Whh0 + ar * HID + 32 * kt + 8 * q, KSC);
        {
            const float2 ww = *(const float2*)(Wih0 + ar * IN0 + 2 * q);
            F8 f; f.p[0] = pkrtz(KSC * ww.x, KSC * ww.y);
            f.p[1] = z2; f.p[2] = z2; f.p[3] = z2;
            wi = f.v;
        }
        #pragma unroll
        for (int r = 0; r < 4; ++r) {
            const int cr = 32 * (mt >> 1) + 4 * (mt & 1) + 8 * q + r;
            bias[r] = KSC * (bih0[cr] + bhh0[cr]);
        }
        const float* xrow = x + ((size_t)(bseq + n)) * T_STEPS * IN0 + 2 * q;
        float2 xb[SS];             // xb[t&7] = x(t) at top of step t
        #pragma unroll
        for (int i = 0; i < SS; ++i)
            xb[i] = *(const float2*)(xrow + i * IN0);

        for (int s = 0; s < NSS; ++s) {
            #pragma unroll
            for (int i = 0; i < SS; ++i) {
                const int t = SS * s + i;
                const int bf = t & 1;
                // (1) chain reads FIRST: both H0(t-1) fragments (4x h4)
                H8Q f0, f1;
                f0.h[0] = X0[bf ^ 1][0][lane]; f0.h[1] = X0[bf ^ 1][1][lane];
                f1.h[0] = X0[bf ^ 1][2][lane]; f1.h[1] = X0[bf ^ 1][3][lane];
                // (2) read shadow: cp = bias + Wih@x(t) (pure register)
                F8 xf; xf.p[0] = pkrtz(xb[i].x, xb[i].y);
                xf.p[1] = z2; xf.p[2] = z2; xf.p[3] = z2;
                f4 cp = MFMA(wi, xf.v, bias);
                int tn = t + SS; if (tn > T_STEPS - 1) tn = T_STEPS - 1;
                xb[i] = *(const float2*)(xrow + tn * IN0);
                // (3) chain: 2 INDEPENDENT MFMA + add (1 MFMA latency, R14)
                f4 ca = MFMA(wh[0], f0.v, cp);
                f4 cb = MFMA(wh[1], f1.v, zero);
                const f4 c = ca + cb;
                H4U u;
                u.p[0] = pkrtz(tanh_pre(c[0]), tanh_pre(c[1]));
                u.p[1] = pkrtz(tanh_pre(c[2]), tanh_pre(c[3]));
                X0[bf][mt][lane] = u.v;
                LDS_BARRIER();
            }
        }
    } else {
        // ---------------- layer-1 quarter-wave ----------------
        // step t computes H1(t-1); ALL inputs are stable bf^1 buffers.
        h8 wa[2], wb[2];           // KSC-scaled
        f4 bias, fcv;
        #pragma unroll
        for (int kt = 0; kt < 2; ++kt) {
            wa[kt] = load_frag_f16_s(Wih1 + ar * HID + 32 * kt + 8 * q, KSC);
            wb[kt] = load_frag_f16_s(Whh1 + ar * HID + 32 * kt + 8 * q, KSC);
        }
        #pragma unroll
        for (int r = 0; r < 4; ++r) {
            const int cr = 32 * (mt >> 1) + 4 * (mt & 1) + 8 * q + r;
            bias[r] = KSC * (bih1[cr] + bhh1[cr]);
            fcv[r]  = fcw[cr];     // unscaled: applied post-tanh
        }
        for (int s = 0; s < NSS; ++s) {
            #pragma unroll
            for (int i = 0; i < SS; ++i) {
                const int t = SS * s + i;
                const int bf = t & 1;
                // chain reads: H0(t-1) and H1(t-2) fragments (8x h4)
                H8Q g0, g1, k0, k1;
                g0.h[0] = X0[bf ^ 1][0][lane]; g0.h[1] = X0[bf ^ 1][1][lane];
                g1.h[0] = X0[bf ^ 1][2][lane]; g1.h[1] = X0[bf ^ 1][3][lane];
                k0.h[0] = X1[bf ^ 1][0][lane]; k0.h[1] = X1[bf ^ 1][1][lane];
                k1.h[0] = X1[bf ^ 1][2][lane]; k1.h[1] = X1[bf ^ 1][3][lane];
                // two INDEPENDENT 2-chains + add (2 MFMA latencies, R14)
                f4 e = MFMA(wa[0], g0.v, bias);
                e    = MFMA(wa[1], g1.v, e);
                f4 g = MFMA(wb[0], k0.v, zero);
                g    = MFMA(wb[1], k1.v, g);
                const f4 d = e + g;
                H4U u;
                u.p[0] = pkrtz(tanh_pre(d[0]), tanh_pre(d[1]));
                u.p[1] = pkrtz(tanh_pre(d[2]), tanh_pre(d[3]));
                // t==0 computes H1(-1) which must stay 0: skip the write
                // (uniform branch, exists only in the i==0 unroll body)
                if (i == 0) {
                    if (s != 0) X1[bf][mt][lane] = u.v;
                } else {
                    X1[bf][mt][lane] = u.v;
                }
                LDS_BARRIER();
            }
        }
        // epilogue: H1(511) from H0(511)=X0[1], H1(510)=X1[1]
        {
            H8Q g0, g1, k0, k1;
            g0.h[0] = X0[1][0][lane]; g0.h[1] = X0[1][1][lane];
            g1.h[0] = X0[1][2][lane]; g1.h[1] = X0[1][3][lane];
            k0.h[0] = X1[1][0][lane]; k0.h[1] = X1[1][1][lane];
            k1.h[0] = X1[1][2][lane]; k1.h[1] = X1[1][3][lane];
            f4 e = MFMA(wa[0], g0.v, bias);
            e    = MFMA(wa[1], g1.v, e);
            f4 g = MFMA(wb[0], k0.v, zero);
            g    = MFMA(wb[1], k1.v, g);
            const f4 d = e + g;
            float sacc = 0.f;
            #pragma unroll
            for (int r = 0; r < 4; ++r) sacc += fcv[r] * tanh_pre(d[r]);
            sacc += __shfl_xor(sacc, 16, 64);
            sacc += __shfl_xor(sacc, 32, 64);
            if (lane < 16) red[mt][n] = sacc;   // q==0 lanes
        }
    }

    __syncthreads();
    if (tid < SPW)
        out[bseq + tid] = red[0][tid] + red[1][tid] + red[2][tid] + red[3][tid] + fcb0;
}

extern "C" void kernel_launch(void* const* d_in, const int* in_sizes, int n_in,
                              void* d_out, int out_size, void* d_ws, size_t ws_size,
                              hipStream_t stream) {
    const float* x    = (const float*)d_in[0];
    const float* Wih0 = (const float*)d_in[1];
    const float* Whh0 = (const float*)d_in[2];
    const float* bih0 = (const float*)d_in[3];
    const float* bhh0 = (const float*)d_in[4];
    const float* Wih1 = (const float*)d_in[5];
    const float* Whh1 = (const float*)d_in[6];
    const float* bih1 = (const float*)d_in[7];
    const float* bhh1 = (const float*)d_in[8];
    const float* fcw  = (const float*)d_in[9];
    const float* fcb  = (const float*)d_in[10];
    float* out = (float*)d_out;

    rnn2_q8s<<<dim3(NBLK), dim3(512), 0, stream>>>(
        x, Wih0, Whh0, bih0, bhh0, Wih1, Whh1, bih1, bhh1, fcw, fcb, out);
}